// Round 26
// baseline (114.792 us; speedup 1.0000x reference)
//
#include <hip/hip_runtime.h>
#include <hip/hip_bf16.h>
#include <hip/hip_fp16.h>

// Problem constants
#define BB 2
#define SS 2048
#define DD 1024
#define HH 16
#define HD 64
#define MM (BB * SS)   // 4096

typedef __attribute__((ext_vector_type(8))) _Float16 half8;
typedef __attribute__((ext_vector_type(4))) float f32x4;
typedef __attribute__((ext_vector_type(4))) short short4v;

static __device__ __forceinline__ short f2h(float f) {
    _Float16 h = (_Float16)f;
    return __builtin_bit_cast(short, h);
}

static __device__ __forceinline__ unsigned pk2(float a, float b) {
    auto h = __builtin_amdgcn_cvt_pkrtz(a, b);
    return __builtin_bit_cast(unsigned, h);
}

// native v_exp_f32 (2^x)
static __device__ __forceinline__ float fexp2(float x) {
    return __builtin_amdgcn_exp2f(x);
}

static __device__ __forceinline__ void gload16(const void* g, void* l) {
    __builtin_amdgcn_global_load_lds(
        (const __attribute__((address_space(1))) unsigned*)g,
        (__attribute__((address_space(3))) unsigned*)l, 16, 0, 0);
}

// 0.125 * log2(e): folded into Q so softmax is p = exp2(score) directly.
#define SC2E 0.18033688011112042f

// ---------------------------------------------------------------------------
// Per-batch stable partition of keys: unmasked first.
// ipos[b*SS + j] = FLAT original row index of compact position j.
// nu[b] = #unmasked; mask16[b][j] = (j < nu) in fp16 (step function).
// ---------------------------------------------------------------------------
__global__ __launch_bounds__(256) void partition_kernel(
    const int* __restrict__ mask, int* __restrict__ ipos,
    short* __restrict__ mask16, int* __restrict__ nu)
{
    const int b = blockIdx.x;
    const int t = threadIdx.x;
    __shared__ int sc[256];
    const int* mrow = mask + b * SS;
    int loc[8];
    int cnt = 0;
    #pragma unroll
    for (int j = 0; j < 8; ++j) { loc[j] = (mrow[t * 8 + j] != 0); cnt += loc[j]; }
    sc[t] = cnt;
    __syncthreads();
    for (int off = 1; off < 256; off <<= 1) {
        const int v = sc[t];
        const int va = (t >= off) ? sc[t - off] : 0;
        __syncthreads();
        sc[t] = v + va;
        __syncthreads();
    }
    const int total = sc[255];
    if (t == 0) nu[b] = total;
    int u = sc[t] - cnt;   // exclusive unmasked prefix
    #pragma unroll
    for (int j = 0; j < 8; ++j) {
        const int s = t * 8 + j;
        const int cp = loc[j] ? u : (total + (s - u));
        ipos[b * SS + cp] = b * SS + s;      // inverse perm, flat
        u += loc[j];
        mask16[b * SS + s] = f2h((s < total) ? 1.0f : 0.0f);
    }
}

// ---------------------------------------------------------------------------
// Combined prepass: fp32 -> fp16 for activations (k/v rows GATHERED to
// compacted order via ipos) and the 4 weight matrices.  grid = (1024, 7).
// ---------------------------------------------------------------------------
__global__ __launch_bounds__(256) void prep_kernel(
    const float* __restrict__ q, const float* __restrict__ k,
    const float* __restrict__ v, const int* __restrict__ ipos,
    const float* __restrict__ wq, const float* __restrict__ wk,
    const float* __restrict__ wv, const float* __restrict__ wo,
    short* __restrict__ q16, short* __restrict__ k16c, short* __restrict__ v16c,
    short* __restrict__ wq16, short* __restrict__ wk16,
    short* __restrict__ wv16, short* __restrict__ wo16)
{
    const int which = blockIdx.y;
    const int t = threadIdx.x;
    if (which >= 3) {
        const float* src; short* dst;
        switch (which) {
            case 3: src = wq; dst = wq16; break;
            case 4: src = wk; dst = wk16; break;
            case 5: src = wv; dst = wv16; break;
            default: src = wo; dst = wo16; break;
        }
        const int i = (blockIdx.x * 256 + t) * 4;
        const float4 f = *(const float4*)&src[i];
        short4v h;
        h.x = f2h(f.x); h.y = f2h(f.y); h.z = f2h(f.z); h.w = f2h(f.w);
        *(short4v*)&dst[i] = h;
        return;
    }
    const float* src = (which == 0) ? q : (which == 1) ? k : v;
    short* dst = (which == 0) ? q16 : (which == 1) ? k16c : v16c;
    const int r0 = blockIdx.x * 4;
    #pragma unroll
    for (int rr = 0; rr < 4; ++rr) {
        const int drow = r0 + rr;
        const int orow = (which == 0) ? drow : ipos[drow];
        const float4 f = *(const float4*)&src[(size_t)orow * DD + t * 4];
        short4v h;
        h.x = f2h(f.x); h.y = f2h(f.y); h.z = f2h(f.z); h.w = f2h(f.w);
        *(short4v*)&dst[(size_t)drow * DD + t * 4] = h;
    }
}

// ---------------------------------------------------------------------------
// fp16 MFMA GEMM (pure fp16 A/W), 2-PHASE PIPELINED, BK=64, XCD-grouped
// mapping.  64 x TN tile, 4 waves (1 x 4 of 64 x TN/4), dbuf LDS.
// TN=64 everywhere: 32 KB LDS -> 5 blocks/CU resident (20 waves/CU);
// QKV grid = 3072 blocks, out-proj = 1024 blocks.  Same 16 barriers/block,
// same (row&7)<<4 swizzle (conflict-free) -- only the B panel narrows.
// mode 0: fp32 (MxN).  mode 1: fp16 split-head (B,H,S,HD), scaled by os.
// mode 2: fp16 (B,H,HD,S) packed b64 store; compact rows >= nu[b] zeroed.
// ---------------------------------------------------------------------------
template<int TN>
static __device__ __forceinline__ void gemm_phase(
    const short* __restrict__ AsCur, const short* __restrict__ BsCur,
    char* AsNxt, char* BsNxt,
    const short* __restrict__ A, const short* __restrict__ W,
    int m0, int n0, int k_next, bool do_stage,
    int t, int lr, int lq, int wc,
    f32x4 acc[4][TN / 64])
{
    constexpr int WN = TN / 4;
    constexpr int NI = TN / 64;
    const int K = DD;

    if (do_stage) {
        #pragma unroll
        for (int c = 0; c < TN / 32; ++c) {
            const int b = c * 4096 + t * 16;
            const int row = b >> 7;
            const int coff = b & 127;
            const int scoff = coff ^ ((row & 7) << 4);
            gload16((const char*)W + ((size_t)(n0 + row) * K + k_next) * 2 + scoff,
                    BsNxt + b);
        }
        #pragma unroll
        for (int c = 0; c < 2; ++c) {
            const int b = c * 4096 + t * 16;
            const int row = b >> 7;
            const int coff = b & 127;
            const int scoff = coff ^ ((row & 7) << 4);
            gload16((const char*)A + ((size_t)(m0 + row) * K + k_next) * 2 + scoff,
                    AsNxt + b);
        }
    }

    half8 af[4][2], bf[NI][2];
    #pragma unroll
    for (int mi = 0; mi < 4; ++mi) {
        const int row = mi * 16 + lr;
        #pragma unroll
        for (int ks = 0; ks < 2; ++ks) {
            const int col = (ks * 32 + lq * 8) ^ ((row & 7) << 3);
            af[mi][ks] = *(const half8*)&AsCur[row * 64 + col];
        }
    }
    #pragma unroll
    for (int ni = 0; ni < NI; ++ni) {
        const int row = wc * WN + ni * 16 + lr;
        #pragma unroll
        for (int ks = 0; ks < 2; ++ks) {
            const int col = (ks * 32 + lq * 8) ^ ((row & 7) << 3);
            bf[ni][ks] = *(const half8*)&BsCur[row * 64 + col];
        }
    }
    __builtin_amdgcn_s_setprio(1);
    #pragma unroll
    for (int ks = 0; ks < 2; ++ks)
        #pragma unroll
        for (int mi = 0; mi < 4; ++mi)
            #pragma unroll
            for (int ni = 0; ni < NI; ++ni)
                acc[mi][ni] = __builtin_amdgcn_mfma_f32_16x16x32_f16(
                    af[mi][ks], bf[ni][ks], acc[mi][ni], 0, 0, 0);
    __builtin_amdgcn_s_setprio(0);

    __syncthreads();
}

template<int TN>
__global__ __launch_bounds__(256) void gemm_f16(
    const short* __restrict__ A0, const short* __restrict__ A1, const short* __restrict__ A2,
    const short* __restrict__ W0, const short* __restrict__ W1, const short* __restrict__ W2,
    const float* __restrict__ b0, const float* __restrict__ b1, const float* __restrict__ b2,
    void* __restrict__ C0, void* __restrict__ C1, void* __restrict__ C2,
    int mode0, int mode1, int mode2,
    float os0, float os1, float os2,
    const int* __restrict__ nu)
{
    constexpr int TM = 64;
    constexpr int WN = TN / 4;
    constexpr int NI = TN / 64;

    // XCD-grouped bijective mapping, n fastest within chunk.
    const int gx = gridDim.x, gy = gridDim.y;
    const int total = gx * gy * gridDim.z;
    const int lin = (blockIdx.z * gy + blockIdx.y) * gx + blockIdx.x;
    const int work = (lin & 7) * (total >> 3) + (lin >> 3);
    const int z = work / (gx * gy);
    const int r0 = work % (gx * gy);
    const int bx = r0 / gy;
    const int by = r0 % gy;

    const short* A = (z == 0) ? A0 : (z == 1) ? A1 : A2;
    const short* W = (z == 0) ? W0 : (z == 1) ? W1 : W2;
    const float* bias = (z == 0) ? b0 : (z == 1) ? b1 : b2;
    void* C = (z == 0) ? C0 : (z == 1) ? C1 : C2;
    const int mode = (z == 0) ? mode0 : (z == 1) ? mode1 : mode2;
    const float os = (z == 0) ? os0 : (z == 1) ? os1 : os2;

    __shared__ short Asw[2][TM * 64];     // 2 x 8 KB
    __shared__ short Bsw[2][TN * 64];     // 2 x (TN/64) x 8 KB

    const int t = threadIdx.x;
    const int wave = t >> 6, lane = t & 63;
    const int lr = lane & 15, lq = lane >> 4;
    const int wc = wave;
    const int m0 = bx * TM, n0 = by * TN;
    const int K = DD;

    f32x4 acc[4][NI] = {};

    // Prologue: stage K-step 0 into buffer 0
    {
        #pragma unroll
        for (int c = 0; c < TN / 32; ++c) {
            const int b = c * 4096 + t * 16;
            const int row = b >> 7;
            const int coff = b & 127;
            const int scoff = coff ^ ((row & 7) << 4);
            gload16((const char*)W + ((size_t)(n0 + row) * K) * 2 + scoff,
                    (char*)Bsw[0] + b);
        }
        #pragma unroll
        for (int c = 0; c < 2; ++c) {
            const int b = c * 4096 + t * 16;
            const int row = b >> 7;
            const int coff = b & 127;
            const int scoff = coff ^ ((row & 7) << 4);
            gload16((const char*)A + ((size_t)(m0 + row) * K) * 2 + scoff,
                    (char*)Asw[0] + b);
        }
    }
    __syncthreads();

    for (int k0 = 0; k0 < K; k0 += 128) {
        gemm_phase<TN>(Asw[0], Bsw[0], (char*)Asw[1], (char*)Bsw[1],
                       A, W, m0, n0, k0 + 64, true,
                       t, lr, lq, wc, acc);
        gemm_phase<TN>(Asw[1], Bsw[1], (char*)Asw[0], (char*)Bsw[0],
                       A, W, m0, n0, k0 + 128, (k0 + 128) < K,
                       t, lr, lq, wc, acc);
    }

    if (mode == 2) {
        // V^T (B,H,HD,S): A rows already compacted -> packed b64 store at 4
        // consecutive compact s; rows >= nu[b] zeroed.
        #pragma unroll
        for (int mi = 0; mi < 4; ++mi) {
            const int m = m0 + mi * 16 + lq * 4;
            const int bidx = m >> 11;
            const int s = m & (SS - 1);
            const int nub = nu[bidx];
            float mmul[4];
            #pragma unroll
            for (int r = 0; r < 4; ++r) mmul[r] = (s + r < nub) ? 1.0f : 0.0f;
            #pragma unroll
            for (int ni = 0; ni < NI; ++ni) {
                const int n = n0 + wc * WN + ni * 16 + lr;
                const int h = n >> 6, d = n & (HD - 1);
                const float bi = bias[n];
                short4v pv;
                pv.x = f2h((acc[mi][ni][0] + bi) * mmul[0]);
                pv.y = f2h((acc[mi][ni][1] + bi) * mmul[1]);
                pv.z = f2h((acc[mi][ni][2] + bi) * mmul[2]);
                pv.w = f2h((acc[mi][ni][3] + bi) * mmul[3]);
                *(short4v*)&((short*)C)[(((size_t)bidx * HH + h) * HD + d) * SS + s] = pv;
            }
        }
    } else {
        #pragma unroll
        for (int mi = 0; mi < 4; ++mi) {
            #pragma unroll
            for (int r = 0; r < 4; ++r) {
                const int m = m0 + mi * 16 + lq * 4 + r;
                const int bidx = m >> 11;
                const int s = m & (SS - 1);
                #pragma unroll
                for (int ni = 0; ni < NI; ++ni) {
                    const int n = n0 + wc * WN + ni * 16 + lr;
                    const float val = (acc[mi][ni][r] + bias[n]) * os;
                    if (mode == 0) {
                        ((float*)C)[(size_t)m * DD + n] = val;
                    } else {
                        const int h = n >> 6, d = n & (HD - 1);
                        ((short*)C)[(((size_t)bidx * HH + h) * SS + s) * HD + d] = f2h(val);
                    }
                }
            }
        }
    }
}

// ---------------------------------------------------------------------------
// MFMA flash attention (fp16) over COMPACTED keys: only ceil(nu/64) tiles.
// Scale folded into Q; l = P @ mask16 (step) MFMA; swapped QK^T; 2-phase dbuf.
// ---------------------------------------------------------------------------
static __device__ __forceinline__ void attn_tile_body(
    const short* __restrict__ Ks, const short* __restrict__ Vts,
    char* KsN, char* VtsN,
    const char* kb, const char* vb,
    int kv_stage, bool do_stage,
    const short* __restrict__ mrow, int kv0,
    const half8 qf[2], short* Pw,
    int t, int lr, int lq,
    f32x4 o[4], f32x4& ol)
{
    if (do_stage) {
        #pragma unroll
        for (int c = 0; c < 2; ++c) {
            const int off = c * 4096 + t * 16;
            const int row = off >> 7, coff = off & 127;
            const int sw = coff ^ ((row & 7) << 4);
            gload16(kb + (size_t)(kv_stage + row) * 128 + sw, KsN + off);
            gload16(vb + (size_t)row * (SS * 2) + kv_stage * 2 + sw, VtsN + off);
        }
    }

    half8 mf[2];
    #pragma unroll
    for (int ks = 0; ks < 2; ++ks)
        mf[ks] = *(const half8*)&mrow[kv0 + ks * 32 + lq * 8];

    f32x4 sc[4] = {};
    __builtin_amdgcn_s_setprio(1);
    #pragma unroll
    for (int kt = 0; kt < 4; ++kt) {
        const int kr = kt * 16 + lr;
        #pragma unroll
        for (int ks = 0; ks < 2; ++ks) {
            half8 kf = *(const half8*)&Ks[kr * 64 + ((ks * 32 + lq * 8) ^ ((kr & 7) << 3))];
            sc[kt] = __builtin_amdgcn_mfma_f32_16x16x32_f16(kf, qf[ks], sc[kt], 0, 0, 0);
        }
    }
    __builtin_amdgcn_s_setprio(0);

    const int xsw = (lr & 7) << 3;
    #pragma unroll
    for (int kt = 0; kt < 4; ++kt) {
        const float p0 = fexp2(sc[kt][0]);
        const float p1 = fexp2(sc[kt][1]);
        const float p2 = fexp2(sc[kt][2]);
        const float p3 = fexp2(sc[kt][3]);
        const int cb = kt * 16 + lq * 4;
        uint2 pp;
        pp.x = pk2(p0, p1);
        pp.y = pk2(p2, p3);
        *(uint2*)&Pw[lr * 64 + (cb ^ xsw)] = pp;
    }

    half8 pf[2];
    #pragma unroll
    for (int ks = 0; ks < 2; ++ks)
        pf[ks] = *(const half8*)&Pw[lr * 64 + ((ks * 32 + lq * 8) ^ xsw)];
    __builtin_amdgcn_s_setprio(1);
    #pragma unroll
    for (int ks = 0; ks < 2; ++ks)
        ol = __builtin_amdgcn_mfma_f32_16x16x32_f16(pf[ks], mf[ks], ol, 0, 0, 0);
    #pragma unroll
    for (int dt = 0; dt < 4; ++dt) {
        const int dr = dt * 16 + lr;
        #pragma unroll
        for (int ks = 0; ks < 2; ++ks) {
            half8 vf = *(const half8*)&Vts[dr * 64 + ((ks * 32 + lq * 8) ^ ((dr & 7) << 3))];
            o[dt] = __builtin_amdgcn_mfma_f32_16x16x32_f16(pf[ks], vf, o[dt], 0, 0, 0);
        }
    }
    __builtin_amdgcn_s_setprio(0);

    __syncthreads();
}

__global__ __launch_bounds__(256) void attn_mfma_kernel(
    const short* __restrict__ q,
    const short* __restrict__ k,
    const short* __restrict__ vt,
    const short* __restrict__ mask16,
    const int* __restrict__ nu,
    short* __restrict__ x)
{
    // XCD-aware swizzle (1024 blocks, 128 per XCD sharing KV streams in L2)
    const int lin = (blockIdx.z * HH + blockIdx.y) * (SS / 64) + blockIdx.x;
    const int swz = (lin & 7) * 128 + (lin >> 3);
    const int qt = swz & 31;
    const int hb = swz >> 5;
    const int h  = hb & (HH - 1);
    const int b  = hb >> 4;

    const int t = threadIdx.x;
    const int wave = t >> 6, lane = t & 63;
    const int lr = lane & 15;
    const int lq = lane >> 4;

    __shared__ short QPs[64 * 64];        // Q tile, then per-wave P tiles
    __shared__ short KsD[2][64 * 64];
    __shared__ short VtsD[2][64 * 64];

    const size_t base  = ((size_t)(b * HH + h)) * SS * HD;
    const size_t basev = ((size_t)(b * HH + h)) * HD * SS;
    const char* kb = (const char*)(k + base);
    const char* vb = (const char*)(vt + basev);

    const int limit = ((nu[b] + 63) >> 6) << 6;

    {
        const char* qb = (const char*)(q + base + (size_t)qt * 64 * HD);
        #pragma unroll
        for (int c = 0; c < 2; ++c) {
            const int off = c * 4096 + t * 16;
            const int row = off >> 7, coff = off & 127;
            const int sw = coff ^ ((row & 7) << 4);
            gload16(qb + row * 128 + sw, (char*)QPs + off);
            gload16(kb + (size_t)row * 128 + sw, (char*)KsD[0] + off);
            gload16(vb + (size_t)row * (SS * 2) + sw, (char*)VtsD[0] + off);
        }
    }
    __syncthreads();

    half8 qf[2];
    #pragma unroll
    for (int ks = 0; ks < 2; ++ks) {
        const int r = wave * 16 + lr;
        qf[ks] = *(const half8*)&QPs[r * 64 + ((ks * 32 + lq * 8) ^ ((r & 7) << 3))];
    }
    __syncthreads();   // all waves done reading Q before P overwrites it

    f32x4 o[4] = {};
    f32x4 ol = {};
    const short* mrow = &mask16[b * SS];
    short* Pw = &QPs[wave * 1024];

    for (int kv0 = 0; kv0 < limit; kv0 += 128) {
        attn_tile_body(KsD[0], VtsD[0], (char*)KsD[1], (char*)VtsD[1],
                       kb, vb, kv0 + 64, (kv0 + 64) < limit,
                       mrow, kv0, qf, Pw, t, lr, lq, o, ol);
        if (kv0 + 64 < limit)
            attn_tile_body(KsD[1], VtsD[1], (char*)KsD[0], (char*)VtsD[0],
                           kb, vb, kv0 + 128, (kv0 + 128) < limit,
                           mrow, kv0 + 64, qf, Pw, t, lr, lq, o, ol);
    }

    float linv[4];
    #pragma unroll
    for (int r = 0; r < 4; ++r) linv[r] = 1.0f / ol[r];
    const int srow = qt * 64 + wave * 16;
    #pragma unroll
    for (int dt = 0; dt < 4; ++dt)
        #pragma unroll
        for (int r = 0; r < 4; ++r)
            x[((size_t)b * SS + srow + lq * 4 + r) * DD + h * HD + dt * 16 + lr] =
                f2h(o[dt][r] * linv[r]);
}

extern "C" void kernel_launch(void* const* d_in, const int* in_sizes, int n_in,
                              void* d_out, int out_size, void* d_ws, size_t ws_size,
                              hipStream_t stream) {
    const float* query = (const float*)d_in[0];
    const float* key   = (const float*)d_in[1];
    const float* value = (const float*)d_in[2];
    const int*   mask  = (const int*)d_in[3];
    const float* Wq = (const float*)d_in[4];
    const float* bq = (const float*)d_in[5];
    const float* Wk = (const float*)d_in[6];
    const float* bk = (const float*)d_in[7];
    const float* Wv = (const float*)d_in[8];
    const float* bv = (const float*)d_in[9];
    const float* Wo = (const float*)d_in[10];
    const float* bo = (const float*)d_in[11];
    float* out = (float*)d_out;

    const size_t NACT = (size_t)MM * DD;   // 4M elements
    const size_t NW   = (size_t)DD * DD;   // 1M elements
    short* wq16   = (short*)d_ws;
    short* wk16   = wq16 + NW;
    short* wv16   = wk16 + NW;
    short* wo16   = wv16 + NW;
    short* q16    = wo16 + NW;
    short* k16c   = q16 + NACT;
    short* v16c   = k16c + NACT;
    short* q_ws   = v16c + NACT;
    short* k_ws   = q_ws + NACT;
    short* vt_ws  = k_ws + NACT;
    short* mask16 = vt_ws + NACT;
    short* x16    = mask16 + BB * SS;
    int*   ipos   = (int*)(x16 + NACT);
    int*   nu     = ipos + BB * SS;

    // 1a. Partition keys (unmasked first) per batch -> inverse perm + nu
    partition_kernel<<<dim3(BB), 256, 0, stream>>>(mask, ipos, mask16, nu);

    // 1b. Combined prepass: activations (k/v gathered compact) + weights
    prep_kernel<<<dim3(MM / 4, 7), 256, 0, stream>>>(
        query, key, value, ipos, Wq, Wk, Wv, Wo,
        q16, k16c, v16c, wq16, wk16, wv16, wo16);

    // 2. Q/K/V projections: TN=64 (3072 blocks, 32 KB LDS, 5 blocks/CU)
    gemm_f16<64><<<dim3(MM / 64, DD / 64, 3), 256, 0, stream>>>(
        q16, k16c, v16c, wq16, wk16, wv16, bq, bk, bv,
        q_ws, k_ws, vt_ws, 1, 1, 2, SC2E, 1.0f, 1.0f, nu);

    // 3. Attention over compacted keys (~half the tiles)
    attn_mfma_kernel<<<dim3(SS / 64, HH, BB), 256, 0, stream>>>(
        q_ws, k_ws, vt_ws, mask16, nu, x16);

    // 4. Output projection: TN=64 (1024 blocks)
    gemm_f16<64><<<dim3(MM / 64, DD / 64, 1), 256, 0, stream>>>(
        x16, x16, x16, wo16, wo16, wo16, bo, bo, bo,
        out, out, out, 0, 0, 0, 1.0f, 1.0f, 1.0f, nu);
}

// Round 27
// 111.836 us; speedup vs baseline: 1.0264x; 1.0264x over previous
//
#include <hip/hip_runtime.h>
#include <hip/hip_bf16.h>
#include <hip/hip_fp16.h>

// Problem constants
#define BB 2
#define SS 2048
#define DD 1024
#define HH 16
#define HD 64
#define MM (BB * SS)   // 4096

typedef __attribute__((ext_vector_type(8))) _Float16 half8;
typedef __attribute__((ext_vector_type(4))) float f32x4;
typedef __attribute__((ext_vector_type(4))) short short4v;

static __device__ __forceinline__ short f2h(float f) {
    _Float16 h = (_Float16)f;
    return __builtin_bit_cast(short, h);
}

static __device__ __forceinline__ unsigned pk2(float a, float b) {
    auto h = __builtin_amdgcn_cvt_pkrtz(a, b);
    return __builtin_bit_cast(unsigned, h);
}

// native v_exp_f32 (2^x)
static __device__ __forceinline__ float fexp2(float x) {
    return __builtin_amdgcn_exp2f(x);
}

static __device__ __forceinline__ void gload16(const void* g, void* l) {
    __builtin_amdgcn_global_load_lds(
        (const __attribute__((address_space(1))) unsigned*)g,
        (__attribute__((address_space(3))) unsigned*)l, 16, 0, 0);
}

// 0.125 * log2(e): folded into Q so softmax is p = exp2(score) directly.
#define SC2E 0.18033688011112042f

// ---------------------------------------------------------------------------
// Per-batch stable partition of keys: unmasked first.
// ipos[b*SS + j] = FLAT original row index of compact position j.
// nu[b] = #unmasked; mask16[b][j] = (j < nu) in fp16 (step function).
// ---------------------------------------------------------------------------
__global__ __launch_bounds__(256) void partition_kernel(
    const int* __restrict__ mask, int* __restrict__ ipos,
    short* __restrict__ mask16, int* __restrict__ nu)
{
    const int b = blockIdx.x;
    const int t = threadIdx.x;
    __shared__ int sc[256];
    const int* mrow = mask + b * SS;
    int loc[8];
    int cnt = 0;
    #pragma unroll
    for (int j = 0; j < 8; ++j) { loc[j] = (mrow[t * 8 + j] != 0); cnt += loc[j]; }
    sc[t] = cnt;
    __syncthreads();
    for (int off = 1; off < 256; off <<= 1) {
        const int v = sc[t];
        const int va = (t >= off) ? sc[t - off] : 0;
        __syncthreads();
        sc[t] = v + va;
        __syncthreads();
    }
    const int total = sc[255];
    if (t == 0) nu[b] = total;
    int u = sc[t] - cnt;   // exclusive unmasked prefix
    #pragma unroll
    for (int j = 0; j < 8; ++j) {
        const int s = t * 8 + j;
        const int cp = loc[j] ? u : (total + (s - u));
        ipos[b * SS + cp] = b * SS + s;      // inverse perm, flat
        u += loc[j];
        mask16[b * SS + s] = f2h((s < total) ? 1.0f : 0.0f);
    }
}

// ---------------------------------------------------------------------------
// Combined prepass: fp32 -> fp16 for activations (k/v rows GATHERED to
// compacted order via ipos) and the 4 weight matrices.  grid = (1024, 7).
// ---------------------------------------------------------------------------
__global__ __launch_bounds__(256) void prep_kernel(
    const float* __restrict__ q, const float* __restrict__ k,
    const float* __restrict__ v, const int* __restrict__ ipos,
    const float* __restrict__ wq, const float* __restrict__ wk,
    const float* __restrict__ wv, const float* __restrict__ wo,
    short* __restrict__ q16, short* __restrict__ k16c, short* __restrict__ v16c,
    short* __restrict__ wq16, short* __restrict__ wk16,
    short* __restrict__ wv16, short* __restrict__ wo16)
{
    const int which = blockIdx.y;
    const int t = threadIdx.x;
    if (which >= 3) {
        const float* src; short* dst;
        switch (which) {
            case 3: src = wq; dst = wq16; break;
            case 4: src = wk; dst = wk16; break;
            case 5: src = wv; dst = wv16; break;
            default: src = wo; dst = wo16; break;
        }
        const int i = (blockIdx.x * 256 + t) * 4;
        const float4 f = *(const float4*)&src[i];
        short4v h;
        h.x = f2h(f.x); h.y = f2h(f.y); h.z = f2h(f.z); h.w = f2h(f.w);
        *(short4v*)&dst[i] = h;
        return;
    }
    const float* src = (which == 0) ? q : (which == 1) ? k : v;
    short* dst = (which == 0) ? q16 : (which == 1) ? k16c : v16c;
    const int r0 = blockIdx.x * 4;
    #pragma unroll
    for (int rr = 0; rr < 4; ++rr) {
        const int drow = r0 + rr;
        const int orow = (which == 0) ? drow : ipos[drow];
        const float4 f = *(const float4*)&src[(size_t)orow * DD + t * 4];
        short4v h;
        h.x = f2h(f.x); h.y = f2h(f.y); h.z = f2h(f.z); h.w = f2h(f.w);
        *(short4v*)&dst[(size_t)drow * DD + t * 4] = h;
    }
}

// ---------------------------------------------------------------------------
// fp16 MFMA GEMM (pure fp16 A/W), 2-PHASE PIPELINED, BK=64, XCD-grouped
// mapping.  64 x TN tile, 4 waves (1 x 4 of 64 x TN/4), dbuf LDS.
// TN=128 (QKV: 1536 blocks, measured 40.2 us); TN=64 (out-proj: 1024
// blocks -- fixes grid starvation of the 512-block TN=128 variant).
// mode 0: fp32 (MxN).  mode 1: fp16 split-head (B,H,S,HD), scaled by os.
// mode 2: fp16 (B,H,HD,S) packed b64 store; compact rows >= nu[b] zeroed.
// ---------------------------------------------------------------------------
template<int TN>
static __device__ __forceinline__ void gemm_phase(
    const short* __restrict__ AsCur, const short* __restrict__ BsCur,
    char* AsNxt, char* BsNxt,
    const short* __restrict__ A, const short* __restrict__ W,
    int m0, int n0, int k_next, bool do_stage,
    int t, int lr, int lq, int wc,
    f32x4 acc[4][TN / 64])
{
    constexpr int WN = TN / 4;
    constexpr int NI = TN / 64;
    const int K = DD;

    if (do_stage) {
        #pragma unroll
        for (int c = 0; c < TN / 32; ++c) {
            const int b = c * 4096 + t * 16;
            const int row = b >> 7;
            const int coff = b & 127;
            const int scoff = coff ^ ((row & 7) << 4);
            gload16((const char*)W + ((size_t)(n0 + row) * K + k_next) * 2 + scoff,
                    BsNxt + b);
        }
        #pragma unroll
        for (int c = 0; c < 2; ++c) {
            const int b = c * 4096 + t * 16;
            const int row = b >> 7;
            const int coff = b & 127;
            const int scoff = coff ^ ((row & 7) << 4);
            gload16((const char*)A + ((size_t)(m0 + row) * K + k_next) * 2 + scoff,
                    AsNxt + b);
        }
    }

    half8 af[4][2], bf[NI][2];
    #pragma unroll
    for (int mi = 0; mi < 4; ++mi) {
        const int row = mi * 16 + lr;
        #pragma unroll
        for (int ks = 0; ks < 2; ++ks) {
            const int col = (ks * 32 + lq * 8) ^ ((row & 7) << 3);
            af[mi][ks] = *(const half8*)&AsCur[row * 64 + col];
        }
    }
    #pragma unroll
    for (int ni = 0; ni < NI; ++ni) {
        const int row = wc * WN + ni * 16 + lr;
        #pragma unroll
        for (int ks = 0; ks < 2; ++ks) {
            const int col = (ks * 32 + lq * 8) ^ ((row & 7) << 3);
            bf[ni][ks] = *(const half8*)&BsCur[row * 64 + col];
        }
    }
    __builtin_amdgcn_s_setprio(1);
    #pragma unroll
    for (int ks = 0; ks < 2; ++ks)
        #pragma unroll
        for (int mi = 0; mi < 4; ++mi)
            #pragma unroll
            for (int ni = 0; ni < NI; ++ni)
                acc[mi][ni] = __builtin_amdgcn_mfma_f32_16x16x32_f16(
                    af[mi][ks], bf[ni][ks], acc[mi][ni], 0, 0, 0);
    __builtin_amdgcn_s_setprio(0);

    __syncthreads();
}

template<int TN>
__global__ __launch_bounds__(256) void gemm_f16(
    const short* __restrict__ A0, const short* __restrict__ A1, const short* __restrict__ A2,
    const short* __restrict__ W0, const short* __restrict__ W1, const short* __restrict__ W2,
    const float* __restrict__ b0, const float* __restrict__ b1, const float* __restrict__ b2,
    void* __restrict__ C0, void* __restrict__ C1, void* __restrict__ C2,
    int mode0, int mode1, int mode2,
    float os0, float os1, float os2,
    const int* __restrict__ nu)
{
    constexpr int TM = 64;
    constexpr int WN = TN / 4;
    constexpr int NI = TN / 64;

    // XCD-grouped bijective mapping, n fastest within chunk.
    const int gx = gridDim.x, gy = gridDim.y;
    const int total = gx * gy * gridDim.z;
    const int lin = (blockIdx.z * gy + blockIdx.y) * gx + blockIdx.x;
    const int work = (lin & 7) * (total >> 3) + (lin >> 3);
    const int z = work / (gx * gy);
    const int r0 = work % (gx * gy);
    const int bx = r0 / gy;
    const int by = r0 % gy;

    const short* A = (z == 0) ? A0 : (z == 1) ? A1 : A2;
    const short* W = (z == 0) ? W0 : (z == 1) ? W1 : W2;
    const float* bias = (z == 0) ? b0 : (z == 1) ? b1 : b2;
    void* C = (z == 0) ? C0 : (z == 1) ? C1 : C2;
    const int mode = (z == 0) ? mode0 : (z == 1) ? mode1 : mode2;
    const float os = (z == 0) ? os0 : (z == 1) ? os1 : os2;

    __shared__ short Asw[2][TM * 64];     // 2 x 8 KB
    __shared__ short Bsw[2][TN * 64];     // 2 x (TN/64) x 8 KB

    const int t = threadIdx.x;
    const int wave = t >> 6, lane = t & 63;
    const int lr = lane & 15, lq = lane >> 4;
    const int wc = wave;
    const int m0 = bx * TM, n0 = by * TN;
    const int K = DD;

    f32x4 acc[4][NI] = {};

    // Prologue: stage K-step 0 into buffer 0
    {
        #pragma unroll
        for (int c = 0; c < TN / 32; ++c) {
            const int b = c * 4096 + t * 16;
            const int row = b >> 7;
            const int coff = b & 127;
            const int scoff = coff ^ ((row & 7) << 4);
            gload16((const char*)W + ((size_t)(n0 + row) * K) * 2 + scoff,
                    (char*)Bsw[0] + b);
        }
        #pragma unroll
        for (int c = 0; c < 2; ++c) {
            const int b = c * 4096 + t * 16;
            const int row = b >> 7;
            const int coff = b & 127;
            const int scoff = coff ^ ((row & 7) << 4);
            gload16((const char*)A + ((size_t)(m0 + row) * K) * 2 + scoff,
                    (char*)Asw[0] + b);
        }
    }
    __syncthreads();

    for (int k0 = 0; k0 < K; k0 += 128) {
        gemm_phase<TN>(Asw[0], Bsw[0], (char*)Asw[1], (char*)Bsw[1],
                       A, W, m0, n0, k0 + 64, true,
                       t, lr, lq, wc, acc);
        gemm_phase<TN>(Asw[1], Bsw[1], (char*)Asw[0], (char*)Bsw[0],
                       A, W, m0, n0, k0 + 128, (k0 + 128) < K,
                       t, lr, lq, wc, acc);
    }

    if (mode == 2) {
        // V^T (B,H,HD,S): A rows already compacted -> packed b64 store at 4
        // consecutive compact s; rows >= nu[b] zeroed.
        #pragma unroll
        for (int mi = 0; mi < 4; ++mi) {
            const int m = m0 + mi * 16 + lq * 4;
            const int bidx = m >> 11;
            const int s = m & (SS - 1);
            const int nub = nu[bidx];
            float mmul[4];
            #pragma unroll
            for (int r = 0; r < 4; ++r) mmul[r] = (s + r < nub) ? 1.0f : 0.0f;
            #pragma unroll
            for (int ni = 0; ni < NI; ++ni) {
                const int n = n0 + wc * WN + ni * 16 + lr;
                const int h = n >> 6, d = n & (HD - 1);
                const float bi = bias[n];
                short4v pv;
                pv.x = f2h((acc[mi][ni][0] + bi) * mmul[0]);
                pv.y = f2h((acc[mi][ni][1] + bi) * mmul[1]);
                pv.z = f2h((acc[mi][ni][2] + bi) * mmul[2]);
                pv.w = f2h((acc[mi][ni][3] + bi) * mmul[3]);
                *(short4v*)&((short*)C)[(((size_t)bidx * HH + h) * HD + d) * SS + s] = pv;
            }
        }
    } else {
        #pragma unroll
        for (int mi = 0; mi < 4; ++mi) {
            #pragma unroll
            for (int r = 0; r < 4; ++r) {
                const int m = m0 + mi * 16 + lq * 4 + r;
                const int bidx = m >> 11;
                const int s = m & (SS - 1);
                #pragma unroll
                for (int ni = 0; ni < NI; ++ni) {
                    const int n = n0 + wc * WN + ni * 16 + lr;
                    const float val = (acc[mi][ni][r] + bias[n]) * os;
                    if (mode == 0) {
                        ((float*)C)[(size_t)m * DD + n] = val;
                    } else {
                        const int h = n >> 6, d = n & (HD - 1);
                        ((short*)C)[(((size_t)bidx * HH + h) * SS + s) * HD + d] = f2h(val);
                    }
                }
            }
        }
    }
}

// ---------------------------------------------------------------------------
// MFMA flash attention (fp16) over COMPACTED keys: only ceil(nu/64) tiles.
// Scale folded into Q; l = P @ mask16 (step) MFMA; swapped QK^T; 2-phase dbuf.
// ---------------------------------------------------------------------------
static __device__ __forceinline__ void attn_tile_body(
    const short* __restrict__ Ks, const short* __restrict__ Vts,
    char* KsN, char* VtsN,
    const char* kb, const char* vb,
    int kv_stage, bool do_stage,
    const short* __restrict__ mrow, int kv0,
    const half8 qf[2], short* Pw,
    int t, int lr, int lq,
    f32x4 o[4], f32x4& ol)
{
    if (do_stage) {
        #pragma unroll
        for (int c = 0; c < 2; ++c) {
            const int off = c * 4096 + t * 16;
            const int row = off >> 7, coff = off & 127;
            const int sw = coff ^ ((row & 7) << 4);
            gload16(kb + (size_t)(kv_stage + row) * 128 + sw, KsN + off);
            gload16(vb + (size_t)row * (SS * 2) + kv_stage * 2 + sw, VtsN + off);
        }
    }

    half8 mf[2];
    #pragma unroll
    for (int ks = 0; ks < 2; ++ks)
        mf[ks] = *(const half8*)&mrow[kv0 + ks * 32 + lq * 8];

    f32x4 sc[4] = {};
    __builtin_amdgcn_s_setprio(1);
    #pragma unroll
    for (int kt = 0; kt < 4; ++kt) {
        const int kr = kt * 16 + lr;
        #pragma unroll
        for (int ks = 0; ks < 2; ++ks) {
            half8 kf = *(const half8*)&Ks[kr * 64 + ((ks * 32 + lq * 8) ^ ((kr & 7) << 3))];
            sc[kt] = __builtin_amdgcn_mfma_f32_16x16x32_f16(kf, qf[ks], sc[kt], 0, 0, 0);
        }
    }
    __builtin_amdgcn_s_setprio(0);

    const int xsw = (lr & 7) << 3;
    #pragma unroll
    for (int kt = 0; kt < 4; ++kt) {
        const float p0 = fexp2(sc[kt][0]);
        const float p1 = fexp2(sc[kt][1]);
        const float p2 = fexp2(sc[kt][2]);
        const float p3 = fexp2(sc[kt][3]);
        const int cb = kt * 16 + lq * 4;
        uint2 pp;
        pp.x = pk2(p0, p1);
        pp.y = pk2(p2, p3);
        *(uint2*)&Pw[lr * 64 + (cb ^ xsw)] = pp;
    }

    half8 pf[2];
    #pragma unroll
    for (int ks = 0; ks < 2; ++ks)
        pf[ks] = *(const half8*)&Pw[lr * 64 + ((ks * 32 + lq * 8) ^ xsw)];
    __builtin_amdgcn_s_setprio(1);
    #pragma unroll
    for (int ks = 0; ks < 2; ++ks)
        ol = __builtin_amdgcn_mfma_f32_16x16x32_f16(pf[ks], mf[ks], ol, 0, 0, 0);
    #pragma unroll
    for (int dt = 0; dt < 4; ++dt) {
        const int dr = dt * 16 + lr;
        #pragma unroll
        for (int ks = 0; ks < 2; ++ks) {
            half8 vf = *(const half8*)&Vts[dr * 64 + ((ks * 32 + lq * 8) ^ ((dr & 7) << 3))];
            o[dt] = __builtin_amdgcn_mfma_f32_16x16x32_f16(pf[ks], vf, o[dt], 0, 0, 0);
        }
    }
    __builtin_amdgcn_s_setprio(0);

    __syncthreads();
}

__global__ __launch_bounds__(256) void attn_mfma_kernel(
    const short* __restrict__ q,
    const short* __restrict__ k,
    const short* __restrict__ vt,
    const short* __restrict__ mask16,
    const int* __restrict__ nu,
    short* __restrict__ x)
{
    // XCD-aware swizzle (1024 blocks, 128 per XCD sharing KV streams in L2)
    const int lin = (blockIdx.z * HH + blockIdx.y) * (SS / 64) + blockIdx.x;
    const int swz = (lin & 7) * 128 + (lin >> 3);
    const int qt = swz & 31;
    const int hb = swz >> 5;
    const int h  = hb & (HH - 1);
    const int b  = hb >> 4;

    const int t = threadIdx.x;
    const int wave = t >> 6, lane = t & 63;
    const int lr = lane & 15;
    const int lq = lane >> 4;

    __shared__ short QPs[64 * 64];        // Q tile, then per-wave P tiles
    __shared__ short KsD[2][64 * 64];
    __shared__ short VtsD[2][64 * 64];

    const size_t base  = ((size_t)(b * HH + h)) * SS * HD;
    const size_t basev = ((size_t)(b * HH + h)) * HD * SS;
    const char* kb = (const char*)(k + base);
    const char* vb = (const char*)(vt + basev);

    const int limit = ((nu[b] + 63) >> 6) << 6;

    {
        const char* qb = (const char*)(q + base + (size_t)qt * 64 * HD);
        #pragma unroll
        for (int c = 0; c < 2; ++c) {
            const int off = c * 4096 + t * 16;
            const int row = off >> 7, coff = off & 127;
            const int sw = coff ^ ((row & 7) << 4);
            gload16(qb + row * 128 + sw, (char*)QPs + off);
            gload16(kb + (size_t)row * 128 + sw, (char*)KsD[0] + off);
            gload16(vb + (size_t)row * (SS * 2) + sw, (char*)VtsD[0] + off);
        }
    }
    __syncthreads();

    half8 qf[2];
    #pragma unroll
    for (int ks = 0; ks < 2; ++ks) {
        const int r = wave * 16 + lr;
        qf[ks] = *(const half8*)&QPs[r * 64 + ((ks * 32 + lq * 8) ^ ((r & 7) << 3))];
    }
    __syncthreads();   // all waves done reading Q before P overwrites it

    f32x4 o[4] = {};
    f32x4 ol = {};
    const short* mrow = &mask16[b * SS];
    short* Pw = &QPs[wave * 1024];

    for (int kv0 = 0; kv0 < limit; kv0 += 128) {
        attn_tile_body(KsD[0], VtsD[0], (char*)KsD[1], (char*)VtsD[1],
                       kb, vb, kv0 + 64, (kv0 + 64) < limit,
                       mrow, kv0, qf, Pw, t, lr, lq, o, ol);
        if (kv0 + 64 < limit)
            attn_tile_body(KsD[1], VtsD[1], (char*)KsD[0], (char*)VtsD[0],
                           kb, vb, kv0 + 128, (kv0 + 128) < limit,
                           mrow, kv0 + 64, qf, Pw, t, lr, lq, o, ol);
    }

    float linv[4];
    #pragma unroll
    for (int r = 0; r < 4; ++r) linv[r] = 1.0f / ol[r];
    const int srow = qt * 64 + wave * 16;
    #pragma unroll
    for (int dt = 0; dt < 4; ++dt)
        #pragma unroll
        for (int r = 0; r < 4; ++r)
            x[((size_t)b * SS + srow + lq * 4 + r) * DD + h * HD + dt * 16 + lr] =
                f2h(o[dt][r] * linv[r]);
}

extern "C" void kernel_launch(void* const* d_in, const int* in_sizes, int n_in,
                              void* d_out, int out_size, void* d_ws, size_t ws_size,
                              hipStream_t stream) {
    const float* query = (const float*)d_in[0];
    const float* key   = (const float*)d_in[1];
    const float* value = (const float*)d_in[2];
    const int*   mask  = (const int*)d_in[3];
    const float* Wq = (const float*)d_in[4];
    const float* bq = (const float*)d_in[5];
    const float* Wk = (const float*)d_in[6];
    const float* bk = (const float*)d_in[7];
    const float* Wv = (const float*)d_in[8];
    const float* bv = (const float*)d_in[9];
    const float* Wo = (const float*)d_in[10];
    const float* bo = (const float*)d_in[11];
    float* out = (float*)d_out;

    const size_t NACT = (size_t)MM * DD;   // 4M elements
    const size_t NW   = (size_t)DD * DD;   // 1M elements
    short* wq16   = (short*)d_ws;
    short* wk16   = wq16 + NW;
    short* wv16   = wk16 + NW;
    short* wo16   = wv16 + NW;
    short* q16    = wo16 + NW;
    short* k16c   = q16 + NACT;
    short* v16c   = k16c + NACT;
    short* q_ws   = v16c + NACT;
    short* k_ws   = q_ws + NACT;
    short* vt_ws  = k_ws + NACT;
    short* mask16 = vt_ws + NACT;
    short* x16    = mask16 + BB * SS;
    int*   ipos   = (int*)(x16 + NACT);
    int*   nu     = ipos + BB * SS;

    // 1a. Partition keys (unmasked first) per batch -> inverse perm + nu
    partition_kernel<<<dim3(BB), 256, 0, stream>>>(mask, ipos, mask16, nu);

    // 1b. Combined prepass: activations (k/v gathered compact) + weights
    prep_kernel<<<dim3(MM / 4, 7), 256, 0, stream>>>(
        query, key, value, ipos, Wq, Wk, Wv, Wo,
        q16, k16c, v16c, wq16, wk16, wv16, wo16);

    // 2. Q/K/V projections: TN=128 (1536 blocks; measured-best 40.2 us)
    gemm_f16<128><<<dim3(MM / 64, DD / 128, 3), 256, 0, stream>>>(
        q16, k16c, v16c, wq16, wk16, wv16, bq, bk, bv,
        q_ws, k_ws, vt_ws, 1, 1, 2, SC2E, 1.0f, 1.0f, nu);

    // 3. Attention over compacted keys (~half the tiles)
    attn_mfma_kernel<<<dim3(SS / 64, HH, BB), 256, 0, stream>>>(
        q_ws, k_ws, vt_ws, mask16, nu, x16);

    // 4. Output projection: TN=64 (1024 blocks; measured-best for this grid)
    gemm_f16<64><<<dim3(MM / 64, DD / 64, 1), 256, 0, stream>>>(
        x16, x16, x16, wo16, wo16, wo16, bo, bo, bo,
        out, out, out, 0, 0, 0, 1.0f, 1.0f, 1.0f, nu);
}